// Round 11
// baseline (225.054 us; speedup 1.0000x reference)
//
#include <hip/hip_runtime.h>
#include <hip/hip_bf16.h>
#include <math.h>

// Problem constants
#define BB 64      // batch
#define SS 256     // click seq len
#define KK 10      // unclick per click
#define DD 64      // emb dim
#define FF 192     // 3*D
#define FH1 200
#define FH2 80
#define BIG_NEG_F (-4294967295.0f)

// LDS strides
#define XSTR 200   // W1t row stride in bf16 (192 + 8 pad)
#define H1STR 104  // H1 / W2t row stride in bf16 (96 + 8 pad)

// folded-weight region per MLP (bf16 elements)
#define W1ELTS (80 * XSTR)          // 16000
#define W2ELTS (48 * H1STR)         // 4992
#define WREG   (W1ELTS + W2ELTS)    // 20992 bf16 = 41984 B

typedef __bf16 bfrag __attribute__((ext_vector_type(8)));
typedef float f32x4 __attribute__((ext_vector_type(4)));

__device__ __forceinline__ float sigm_(float x) { return 1.0f / (1.0f + __expf(-x)); }

// ---------------------------------------------------------------------------
// Prep: fold W1 (256x80) -> W1t[n][k]; pad cols zeroed; W2 -> W2t[n][k].
// Grid (3, 40).
// ---------------------------------------------------------------------------
__global__ __launch_bounds__(256) void k_prep(
    const float* __restrict__ sW1, const float* __restrict__ sW2,
    const float* __restrict__ cW1, const float* __restrict__ cW2,
    const float* __restrict__ uW1, const float* __restrict__ uW2,
    __bf16* __restrict__ Wt)
{
    const int p = blockIdx.x, g = blockIdx.y;
    const float* W1 = (p == 0) ? sW1 : (p == 1) ? cW1 : uW1;   // [256][80]
    const float* W2 = (p == 0) ? sW2 : (p == 1) ? cW2 : uW2;   // [80][40]
    __bf16* o1 = Wt + p * WREG;
    __bf16* o2 = o1 + W1ELTS;
    for (int e = g * 256 + threadIdx.x; e < 200 * 80; e += 10240) {
        const int k = e / 80, n = e % 80;
        float v;
        if (k < 64)       v = W1[k * 80 + n] + W1[(k + 128) * 80 + n];
        else if (k < 128) v = W1[k * 80 + n] - W1[(k + 64) * 80 + n];
        else if (k < 192) v = W1[(k + 64) * 80 + n];
        else              v = 0.0f;   // pad
        o1[n * XSTR + k] = (__bf16)v;
    }
    for (int e = g * 256 + threadIdx.x; e < W2ELTS; e += 10240) {
        const int n = e / H1STR, k = e % H1STR;
        o2[e] = (__bf16)((n < 40 && k < 80) ? W2[k * 40 + n] : 0.0f);
    }
}

// ---------------------------------------------------------------------------
// Wave-level MLP core (A-frags in registers, H1 via wave-private LDS slice,
// layer2 B in registers, layer3 via shfl butterfly). score[rg] valid l15==0.
// ---------------------------------------------------------------------------
__device__ __forceinline__ void mlp_core(
    const float* qv, const float* fv,
    const __bf16* __restrict__ sW1, __bf16* __restrict__ sH1w,
    const bfrag* wb2, const float* b1v, const float* b2v, const float* w3v,
    int quad, int l15, float* score)
{
    bfrag af[6];
    #pragma unroll
    for (int j = 0; j < 8; ++j) {
        af[0][j] = (__bf16)qv[j];
        af[1][j] = (__bf16)qv[8 + j];
        af[2][j] = (__bf16)fv[j];
        af[3][j] = (__bf16)fv[8 + j];
        af[4][j] = (__bf16)(qv[j] * fv[j]);
        af[5][j] = (__bf16)(qv[8 + j] * fv[8 + j]);
    }

    f32x4 acc[5];
    #pragma unroll
    for (int nt = 0; nt < 5; ++nt) acc[nt] = (f32x4){0.f, 0.f, 0.f, 0.f};
    {
        const __bf16* wbase = sW1 + l15 * XSTR + quad * 8;
        #pragma unroll
        for (int nt = 0; nt < 5; ++nt) {
            const __bf16* wp = wbase + nt * 16 * XSTR;
            #pragma unroll
            for (int kc = 0; kc < 6; ++kc)
                acc[nt] = __builtin_amdgcn_mfma_f32_16x16x32_bf16(
                    af[kc], *(const bfrag*)(wp + kc * 32), acc[nt], 0, 0, 0);
        }
    }

    #pragma unroll
    for (int nt = 0; nt < 5; ++nt) {
        #pragma unroll
        for (int rg = 0; rg < 4; ++rg)
            sH1w[(quad * 4 + rg) * H1STR + nt * 16 + l15] =
                (__bf16)sigm_(acc[nt][rg] + b1v[nt]);
    }
    #pragma unroll
    for (int rg = 0; rg < 4; ++rg)
        sH1w[(quad * 4 + rg) * H1STR + 80 + l15] = (__bf16)0.0f;

    bfrag af2[3];
    {
        const __bf16* hrow = sH1w + l15 * H1STR + quad * 8;
        #pragma unroll
        for (int kc = 0; kc < 3; ++kc) af2[kc] = *(const bfrag*)(hrow + kc * 32);
    }
    f32x4 acc2[3];
    #pragma unroll
    for (int nt = 0; nt < 3; ++nt) acc2[nt] = (f32x4){0.f, 0.f, 0.f, 0.f};
    #pragma unroll
    for (int nt = 0; nt < 3; ++nt)
        #pragma unroll
        for (int kc = 0; kc < 3; ++kc)
            acc2[nt] = __builtin_amdgcn_mfma_f32_16x16x32_bf16(
                af2[kc], wb2[nt * 3 + kc], acc2[nt], 0, 0, 0);

    float part[4] = {0.f, 0.f, 0.f, 0.f};
    #pragma unroll
    for (int nt = 0; nt < 3; ++nt) {
        #pragma unroll
        for (int rg = 0; rg < 4; ++rg)
            part[rg] += sigm_(acc2[nt][rg] + b2v[nt]) * w3v[nt];
    }
    #pragma unroll
    for (int off = 1; off < 16; off <<= 1) {
        #pragma unroll
        for (int rg = 0; rg < 4; ++rg)
            part[rg] += __shfl_xor(part[rg], off, 64);
    }
    #pragma unroll
    for (int rg = 0; rg < 4; ++rg) score[rg] = part[rg];
}

// ---------------------------------------------------------------------------
// DIN-0 + reduceK, one generation, SINGLE-buffered (anti-spill). Grid 512 x
// 256 threads (4 waves). Wave owns 80 rows = 5 tiles = 8 bs; sH1/ssc are
// wave-private -> no block barrier after the weight stage. #pragma unroll 1
// on outer loops prevents compiler-recreated double buffering (round-8 spill).
// ---------------------------------------------------------------------------
__global__ __launch_bounds__(256) void k_din0(
    const int* __restrict__ click_his, const int* __restrict__ unclick_his,
    const float* __restrict__ click_mask, const float* __restrict__ unclick_mask,
    const float* __restrict__ emb, const __bf16* __restrict__ Wt,
    const float* __restrict__ b1, const float* __restrict__ b2,
    const float* __restrict__ W3, const float* __restrict__ b3,
    float* __restrict__ unatt, float* __restrict__ coef)
{
    __shared__ __align__(16) __bf16 sW1[80 * XSTR];        // 32000 B
    __shared__ __align__(16) __bf16 sH1[4][16 * H1STR];    // 13312 B
    __shared__ float ssc[4][80];                           // 1280 B

    const int t = threadIdx.x;
    const int wave = t >> 6, lane = t & 63;
    const int quad = lane >> 4, l15 = lane & 15;

    // stage W1 once per block
    {
        const uint4* s1 = (const uint4*)Wt;
        uint4* d1 = (uint4*)sW1;
        for (int e = t; e < W1ELTS / 8; e += 256) d1[e] = s1[e];
    }

    // per-wave register weights
    bfrag wb2[9];
    float b1v[5], b2v[3], w3v[3];
    {
        const __bf16* w2g = Wt + W1ELTS;
        #pragma unroll
        for (int nt = 0; nt < 3; ++nt)
            #pragma unroll
            for (int kc = 0; kc < 3; ++kc)
                wb2[nt * 3 + kc] = *(const bfrag*)(w2g + (nt * 16 + l15) * H1STR + kc * 32 + quad * 8);
        #pragma unroll
        for (int nt = 0; nt < 5; ++nt) b1v[nt] = b1[nt * 16 + l15];
        #pragma unroll
        for (int nt = 0; nt < 3; ++nt) {
            const int n = nt * 16 + l15;
            b2v[nt] = (n < 40) ? b2[n] : 0.0f;
            w3v[nt] = (n < 40) ? W3[n] : 0.0f;
        }
    }
    const float b3v = b3[0];

    const int wbase = (blockIdx.x * 4 + wave) * 80;   // first row of this wave
    const int c = quad * 8;
    __syncthreads();   // weights staged — the only block barrier

    // 5 tiles per wave, single-buffered
    #pragma unroll 1
    for (int tt = 0; tt < 5; ++tt) {
        float qv[16], fv[16];
        {
            const int m  = wbase + tt * 16 + l15;
            const int bs = m / 10;
            const float* qp = emb + (size_t)click_his[bs] * DD;
            const float* fp = emb + (size_t)unclick_his[m] * DD;
            const float qs = click_mask[bs], fs = unclick_mask[m];
            *(float4*)(qv + 0)  = *(const float4*)(qp + c);
            *(float4*)(qv + 4)  = *(const float4*)(qp + c + 4);
            *(float4*)(qv + 8)  = *(const float4*)(qp + 32 + c);
            *(float4*)(qv + 12) = *(const float4*)(qp + 32 + c + 4);
            *(float4*)(fv + 0)  = *(const float4*)(fp + c);
            *(float4*)(fv + 4)  = *(const float4*)(fp + c + 4);
            *(float4*)(fv + 8)  = *(const float4*)(fp + 32 + c);
            *(float4*)(fv + 12) = *(const float4*)(fp + 32 + c + 4);
            #pragma unroll
            for (int i = 0; i < 16; ++i) { qv[i] *= qs; fv[i] *= fs; }
        }
        float score[4];
        mlp_core(qv, fv, sW1, sH1[wave], wb2, b1v, b2v, w3v, quad, l15, score);
        if (l15 == 0) {
            #pragma unroll
            for (int rg = 0; rg < 4; ++rg) {
                const int r2 = tt * 16 + quad * 4 + rg;
                const int m2 = wbase + r2;
                ssc[wave][r2] = (unclick_mask[m2] == 1.0f) ? (score[rg] + b3v) : BIG_NEG_F;
            }
        }
    }

    // reduceK: wave-private 8 bs (ssc[wave] written by this wave; within-wave
    // LDS ordering is compiler-guaranteed, same as sH1 in mlp_core)
    #pragma unroll 1
    for (int j = 0; j < 8; ++j) {
        const int bsj = blockIdx.x * 32 + wave * 8 + j;
        float a[KK];
        float mx = -INFINITY;
        #pragma unroll
        for (int k = 0; k < KK; ++k) { a[k] = ssc[wave][j * KK + k]; mx = fmaxf(mx, a[k]); }
        float sum = 0.0f;
        #pragma unroll
        for (int k = 0; k < KK; ++k) { a[k] = __expf(a[k] - mx); sum += a[k]; }
        const float inv = 1.0f / sum;
        float acc3 = 0.0f;
        #pragma unroll
        for (int k = 0; k < KK; ++k) {
            const int off = bsj * KK + k;
            acc3 += a[k] * (emb[(size_t)unclick_his[off] * DD + lane] * unclick_mask[off]);
        }
        acc3 *= inv;
        unatt[(size_t)bsj * DD + lane] = acc3;
        const float qv2 = emb[(size_t)click_his[bsj] * DD + lane] * click_mask[bsj];
        float dp = acc3 * qv2, nq = qv2 * qv2;
        #pragma unroll
        for (int o = 32; o > 0; o >>= 1) {
            dp += __shfl_down(dp, o, 64);
            nq += __shfl_down(nq, o, 64);
        }
        if (lane == 0) coef[bsj] = 1.0f + dp / (nq + 1e-12f);
    }
}

// ---------------------------------------------------------------------------
// DIN-1 + DIN-2: grid (128, 2), 256 threads (4 waves), 2 tiles/wave
// (128 rows/block). Single weight stage, no post-stage barriers.
// ---------------------------------------------------------------------------
__global__ __launch_bounds__(256) void k_din12(
    const int* __restrict__ mid, const int* __restrict__ click_his,
    const float* __restrict__ click_mask,
    const float* __restrict__ emb, const float* __restrict__ unatt,
    const float* __restrict__ coef, const __bf16* __restrict__ Wt,
    const float* __restrict__ cb1, const float* __restrict__ cb2,
    const float* __restrict__ cW3, const float* __restrict__ cb3,
    const float* __restrict__ ub1, const float* __restrict__ ub2,
    const float* __restrict__ uW3, const float* __restrict__ ub3,
    float* __restrict__ scores_c, float* __restrict__ scores_u)
{
    __shared__ __align__(16) __bf16 sW1[80 * XSTR];        // 32000 B
    __shared__ __align__(16) __bf16 sH1[4][16 * H1STR];    // 13312 B

    const int t = threadIdx.x;
    const int mode = blockIdx.y;
    const int wave = t >> 6, lane = t & 63;
    const int quad = lane >> 4, l15 = lane & 15;

    const float* b1 = mode ? ub1 : cb1;
    const float* b2 = mode ? ub2 : cb2;
    const float* W3 = mode ? uW3 : cW3;
    const float* b3 = mode ? ub3 : cb3;
    const __bf16* wreg = Wt + (mode + 1) * WREG;

    {
        const uint4* s1 = (const uint4*)wreg;
        uint4* d1 = (uint4*)sW1;
        for (int e = t; e < W1ELTS / 8; e += 256) d1[e] = s1[e];
    }

    bfrag wb2[9];
    float b1v[5], b2v[3], w3v[3];
    {
        const __bf16* w2g = wreg + W1ELTS;
        #pragma unroll
        for (int nt = 0; nt < 3; ++nt)
            #pragma unroll
            for (int kc = 0; kc < 3; ++kc)
                wb2[nt * 3 + kc] = *(const bfrag*)(w2g + (nt * 16 + l15) * H1STR + kc * 32 + quad * 8);
        #pragma unroll
        for (int nt = 0; nt < 5; ++nt) b1v[nt] = b1[nt * 16 + l15];
        #pragma unroll
        for (int nt = 0; nt < 3; ++nt) {
            const int n = nt * 16 + l15;
            b2v[nt] = (n < 40) ? b2[n] : 0.0f;
            w3v[nt] = (n < 40) ? W3[n] : 0.0f;
        }
    }
    const float b3v = b3[0];
    const int c = quad * 8;
    __syncthreads();   // weights staged

    #pragma unroll 1
    for (int tt = 0; tt < 2; ++tt) {
        const int row = wave * 32 + tt * 16 + l15;       // 0..127
        const int m   = blockIdx.x * 128 + row;
        const int b   = m >> 8;
        float qv[16], fv[16];
        {
            const float* qp = emb + (size_t)mid[b] * DD;
            const float* fp; float fs;
            if (mode == 0) { fp = emb + (size_t)click_his[m] * DD; fs = click_mask[m] * coef[m]; }
            else           { fp = unatt + (size_t)m * DD; fs = 1.0f; }
            *(float4*)(qv + 0)  = *(const float4*)(qp + c);
            *(float4*)(qv + 4)  = *(const float4*)(qp + c + 4);
            *(float4*)(qv + 8)  = *(const float4*)(qp + 32 + c);
            *(float4*)(qv + 12) = *(const float4*)(qp + 32 + c + 4);
            *(float4*)(fv + 0)  = *(const float4*)(fp + c);
            *(float4*)(fv + 4)  = *(const float4*)(fp + c + 4);
            *(float4*)(fv + 8)  = *(const float4*)(fp + 32 + c);
            *(float4*)(fv + 12) = *(const float4*)(fp + 32 + c + 4);
            #pragma unroll
            for (int i = 0; i < 16; ++i) fv[i] *= fs;
        }
        float score[4];
        mlp_core(qv, fv, sW1, sH1[wave], wb2, b1v, b2v, w3v, quad, l15, score);
        if (l15 == 0) {
            float* dst = mode ? scores_u : scores_c;
            #pragma unroll
            for (int rg = 0; rg < 4; ++rg) {
                const int m2 = blockIdx.x * 128 + wave * 32 + tt * 16 + quad * 4 + rg;
                dst[m2] = (click_mask[m2] == 1.0f) ? (score[rg] + b3v) : BIG_NEG_F;
            }
        }
    }
}

// ---------------------------------------------------------------------------
// Tail: grid B=64 x 1024 threads (16 waves).
// ---------------------------------------------------------------------------
__global__ __launch_bounds__(1024) void k_tail(
    const int* __restrict__ mid, const int* __restrict__ click_his,
    const float* __restrict__ click_mask,
    const float* __restrict__ emb, const float* __restrict__ unatt,
    const float* __restrict__ coef,
    const float* __restrict__ scores_c, const float* __restrict__ scores_u,
    const float* __restrict__ bn_g, const float* __restrict__ bn_b,
    const float* __restrict__ bn_m, const float* __restrict__ bn_v,
    const float* __restrict__ fW1, const float* __restrict__ fb1, const float* __restrict__ a1,
    const float* __restrict__ fW2, const float* __restrict__ fb2, const float* __restrict__ a2,
    const float* __restrict__ fW3, const float* __restrict__ fb3,
    float* __restrict__ out)
{
    const int b = blockIdx.x, t = threadIdx.x;
    const int wave = t >> 6, lane = t & 63;
    const int ty = wave >> 3, w8 = wave & 7;
    const int s0 = w8 * 32;

    __shared__ float sa[2][SS];
    __shared__ float smax[16], ssum[16];
    __shared__ float part[16][72];
    __shared__ float x[FF];
    __shared__ float ph1[4][FH1];
    __shared__ float h1s[FH1];
    __shared__ float ph2[8][FH2];
    __shared__ float h2s[FH2];
    __shared__ float red2[2];

    if (t < DD) x[t] = emb[(size_t)mid[b] * DD + t];

    const float* scp = ty ? scores_u : scores_c;
    const float sc = (lane < 32) ? scp[b * SS + s0 + lane] : -INFINITY;
    float mloc = sc;
    #pragma unroll
    for (int o = 32; o > 0; o >>= 1) mloc = fmaxf(mloc, __shfl_xor(mloc, o, 64));
    if (lane == 0) smax[wave] = mloc;
    __syncthreads();

    float mt = smax[ty * 8];
    #pragma unroll
    for (int i = 1; i < 8; ++i) mt = fmaxf(mt, smax[ty * 8 + i]);
    const float e = (lane < 32) ? __expf(sc - mt) : 0.0f;
    if (lane < 32) sa[ty][s0 + lane] = e;
    float sloc = e;
    #pragma unroll
    for (int o = 32; o > 0; o >>= 1) sloc += __shfl_xor(sloc, o, 64);
    if (lane == 0) ssum[wave] = sloc;
    __syncthreads();

    float den = 0.0f;
    #pragma unroll
    for (int i = 0; i < 8; ++i) den += ssum[ty * 8 + i];
    const float inv = 1.0f / den;

    float acc = 0.0f;
    #pragma unroll 8
    for (int i = 0; i < 32; ++i) {
        const int s2 = s0 + i;
        const int bs = b * SS + s2;
        const float fv = ty ? unatt[(size_t)bs * DD + lane]
                            : emb[(size_t)click_his[bs] * DD + lane] * click_mask[bs] * coef[bs];
        acc += sa[ty][s2] * fv;
    }
    part[wave][lane] = acc * inv;
    __syncthreads();

    if (t < 128) {
        const int tt = t >> 6, d = t & 63;
        float v = 0.0f;
        #pragma unroll
        for (int i = 0; i < 8; ++i) v += part[tt * 8 + i][d];
        x[DD + tt * DD + d] = v;
    }
    __syncthreads();

    if (t < FF) x[t] = (x[t] - bn_m[t]) * rsqrtf(bn_v[t] + 1e-3f) * bn_g[t] + bn_b[t];
    __syncthreads();

    if (t < 800) {
        const int n = t % FH1, cc = t / FH1;
        float p = 0.0f;
        #pragma unroll 8
        for (int i = cc * 48; i < cc * 48 + 48; ++i) p += x[i] * fW1[i * FH1 + n];
        ph1[cc][n] = p;
    }
    __syncthreads();
    if (t < FH1) {
        const float a = ph1[0][t] + ph1[1][t] + ph1[2][t] + ph1[3][t] + fb1[t];
        h1s[t] = fmaxf(a, 0.0f) + a1[t] * fminf(a, 0.0f);
    }
    __syncthreads();

    if (t < 640) {
        const int n = t % FH2, cc = t / FH2;
        float p = 0.0f;
        #pragma unroll 5
        for (int i = cc * 25; i < cc * 25 + 25; ++i) p += h1s[i] * fW2[i * FH2 + n];
        ph2[cc][n] = p;
    }
    __syncthreads();
    if (t < FH2) {
        float a = fb2[t];
        #pragma unroll
        for (int cc = 0; cc < 8; ++cc) a += ph2[cc][t];
        h2s[t] = fmaxf(a, 0.0f) + a2[t] * fminf(a, 0.0f);
    }
    __syncthreads();

    if (t < 128) {
        const int o = t >> 6;
        float p = h2s[lane] * fW3[lane * 2 + o];
        if (lane < 16) p += h2s[64 + lane] * fW3[(64 + lane) * 2 + o];
        #pragma unroll
        for (int off = 32; off > 0; off >>= 1) p += __shfl_down(p, off, 64);
        if (lane == 0) red2[o] = p + fb3[o];
    }
    __syncthreads();
    if (t == 0) {
        const float l0 = red2[0], l1 = red2[1];
        const float mx = fmaxf(l0, l1);
        const float e0 = __expf(l0 - mx), e1 = __expf(l1 - mx);
        const float invs = 1.0f / (e0 + e1);
        out[b * 2 + 0] = e0 * invs + 1e-8f;
        out[b * 2 + 1] = e1 * invs + 1e-8f;
    }
}

// ---------------------------------------------------------------------------
extern "C" void kernel_launch(void* const* d_in, const int* in_sizes, int n_in,
                              void* d_out, int out_size, void* d_ws, size_t ws_size,
                              hipStream_t stream) {
    const int*   mid          = (const int*)d_in[0];
    const int*   click_his    = (const int*)d_in[1];
    const int*   unclick_his  = (const int*)d_in[2];
    const float* click_mask   = (const float*)d_in[3];
    const float* unclick_mask = (const float*)d_in[4];
    const float* emb          = (const float*)d_in[5];
    const float* sW1 = (const float*)d_in[6];  const float* sb1 = (const float*)d_in[7];
    const float* sW2 = (const float*)d_in[8];  const float* sb2 = (const float*)d_in[9];
    const float* sW3 = (const float*)d_in[10]; const float* sb3 = (const float*)d_in[11];
    const float* cW1 = (const float*)d_in[12]; const float* cb1 = (const float*)d_in[13];
    const float* cW2 = (const float*)d_in[14]; const float* cb2 = (const float*)d_in[15];
    const float* cW3 = (const float*)d_in[16]; const float* cb3 = (const float*)d_in[17];
    const float* uW1 = (const float*)d_in[18]; const float* ub1 = (const float*)d_in[19];
    const float* uW2 = (const float*)d_in[20]; const float* ub2 = (const float*)d_in[21];
    const float* uW3 = (const float*)d_in[22]; const float* ub3 = (const float*)d_in[23];
    const float* bn_g = (const float*)d_in[24]; const float* bn_b = (const float*)d_in[25];
    const float* bn_m = (const float*)d_in[26]; const float* bn_v = (const float*)d_in[27];
    const float* fW1 = (const float*)d_in[28]; const float* fb1 = (const float*)d_in[29];
    const float* a1  = (const float*)d_in[30];
    const float* fW2 = (const float*)d_in[31]; const float* fb2 = (const float*)d_in[32];
    const float* a2  = (const float*)d_in[33];
    const float* fW3 = (const float*)d_in[34]; const float* fb3 = (const float*)d_in[35];

    float* out = (float*)d_out;

    // Workspace layout (bytes, 16B-aligned)
    char* w = (char*)d_ws;
    __bf16* Wt      = (__bf16*)(w + 0);       // 125952 B
    float* scores_c = (float*)(w + 125952);   // 65536 B
    float* scores_u = (float*)(w + 191488);   // 65536 B
    float* coef     = (float*)(w + 257024);   // 65536 B
    float* unatt    = (float*)(w + 322560);   // 4194304 B

    hipLaunchKernelGGL(k_prep, dim3(3, 40), dim3(256), 0, stream,
        sW1, sW2, cW1, cW2, uW1, uW2, Wt);

    hipLaunchKernelGGL(k_din0, dim3(512), dim3(256), 0, stream,
        click_his, unclick_his, click_mask, unclick_mask, emb, Wt,
        sb1, sb2, sW3, sb3, unatt, coef);

    hipLaunchKernelGGL(k_din12, dim3(128, 2), dim3(256), 0, stream,
        mid, click_his, click_mask, emb, unatt, coef, Wt,
        cb1, cb2, cW3, cb3, ub1, ub2, uW3, ub3, scores_c, scores_u);

    hipLaunchKernelGGL(k_tail, dim3(BB), dim3(1024), 0, stream,
        mid, click_his, click_mask, emb, unatt, coef, scores_c, scores_u,
        bn_g, bn_b, bn_m, bn_v, fW1, fb1, a1, fW2, fb2, a2, fW3, fb3, out);
}

// Round 12
// 224.025 us; speedup vs baseline: 1.0046x; 1.0046x over previous
//
#include <hip/hip_runtime.h>
#include <hip/hip_bf16.h>
#include <math.h>

// Problem constants
#define BB 64      // batch
#define SS 256     // click seq len
#define KK 10      // unclick per click
#define DD 64      // emb dim
#define FF 192     // 3*D
#define FH1 200
#define FH2 80
#define BIG_NEG_F (-4294967295.0f)

// LDS strides
#define XSTR 200   // W1t row stride in bf16 (192 + 8 pad)
#define H1STR 104  // H1 / W2t row stride in bf16 (96 + 8 pad)

// folded-weight region per MLP (bf16 elements)
#define W1ELTS (80 * XSTR)          // 16000
#define W2ELTS (48 * H1STR)         // 4992
#define WREG   (W1ELTS + W2ELTS)    // 20992 bf16 = 41984 B

typedef __bf16 bfrag __attribute__((ext_vector_type(8)));
typedef float f32x4 __attribute__((ext_vector_type(4)));

__device__ __forceinline__ float sigm_(float x) { return 1.0f / (1.0f + __expf(-x)); }

// ---------------------------------------------------------------------------
// Prep: fold W1 (256x80) -> W1t[n][k]; pad cols zeroed; W2 -> W2t[n][k].
// ---------------------------------------------------------------------------
__global__ __launch_bounds__(256) void k_prep(
    const float* __restrict__ sW1, const float* __restrict__ sW2,
    const float* __restrict__ cW1, const float* __restrict__ cW2,
    const float* __restrict__ uW1, const float* __restrict__ uW2,
    __bf16* __restrict__ Wt)
{
    const int p = blockIdx.x, g = blockIdx.y;
    const float* W1 = (p == 0) ? sW1 : (p == 1) ? cW1 : uW1;   // [256][80]
    const float* W2 = (p == 0) ? sW2 : (p == 1) ? cW2 : uW2;   // [80][40]
    __bf16* o1 = Wt + p * WREG;
    __bf16* o2 = o1 + W1ELTS;
    for (int e = g * 256 + threadIdx.x; e < 200 * 80; e += 10240) {
        const int k = e / 80, n = e % 80;
        float v;
        if (k < 64)       v = W1[k * 80 + n] + W1[(k + 128) * 80 + n];
        else if (k < 128) v = W1[k * 80 + n] - W1[(k + 64) * 80 + n];
        else if (k < 192) v = W1[(k + 64) * 80 + n];
        else              v = 0.0f;
        o1[n * XSTR + k] = (__bf16)v;
    }
    for (int e = g * 256 + threadIdx.x; e < W2ELTS; e += 10240) {
        const int n = e / H1STR, k = e % H1STR;
        o2[e] = (__bf16)((n < 40 && k < 80) ? W2[k * 40 + n] : 0.0f);
    }
}

// ---------------------------------------------------------------------------
// Wave-level MLP core. score[rg] valid on l15==0 lanes.
// ---------------------------------------------------------------------------
__device__ __forceinline__ void mlp_core(
    const float* qv, const float* fv,
    const __bf16* __restrict__ sW1, __bf16* __restrict__ sH1w,
    const bfrag* wb2, const float* b1v, const float* b2v, const float* w3v,
    int quad, int l15, float* score)
{
    bfrag af[6];
    #pragma unroll
    for (int j = 0; j < 8; ++j) {
        af[0][j] = (__bf16)qv[j];
        af[1][j] = (__bf16)qv[8 + j];
        af[2][j] = (__bf16)fv[j];
        af[3][j] = (__bf16)fv[8 + j];
        af[4][j] = (__bf16)(qv[j] * fv[j]);
        af[5][j] = (__bf16)(qv[8 + j] * fv[8 + j]);
    }

    f32x4 acc[5];
    #pragma unroll
    for (int nt = 0; nt < 5; ++nt) acc[nt] = (f32x4){0.f, 0.f, 0.f, 0.f};
    {
        const __bf16* wbase = sW1 + l15 * XSTR + quad * 8;
        #pragma unroll
        for (int nt = 0; nt < 5; ++nt) {
            const __bf16* wp = wbase + nt * 16 * XSTR;
            #pragma unroll
            for (int kc = 0; kc < 6; ++kc)
                acc[nt] = __builtin_amdgcn_mfma_f32_16x16x32_bf16(
                    af[kc], *(const bfrag*)(wp + kc * 32), acc[nt], 0, 0, 0);
        }
    }

    #pragma unroll
    for (int nt = 0; nt < 5; ++nt) {
        #pragma unroll
        for (int rg = 0; rg < 4; ++rg)
            sH1w[(quad * 4 + rg) * H1STR + nt * 16 + l15] =
                (__bf16)sigm_(acc[nt][rg] + b1v[nt]);
    }
    #pragma unroll
    for (int rg = 0; rg < 4; ++rg)
        sH1w[(quad * 4 + rg) * H1STR + 80 + l15] = (__bf16)0.0f;

    bfrag af2[3];
    {
        const __bf16* hrow = sH1w + l15 * H1STR + quad * 8;
        #pragma unroll
        for (int kc = 0; kc < 3; ++kc) af2[kc] = *(const bfrag*)(hrow + kc * 32);
    }
    f32x4 acc2[3];
    #pragma unroll
    for (int nt = 0; nt < 3; ++nt) acc2[nt] = (f32x4){0.f, 0.f, 0.f, 0.f};
    #pragma unroll
    for (int nt = 0; nt < 3; ++nt)
        #pragma unroll
        for (int kc = 0; kc < 3; ++kc)
            acc2[nt] = __builtin_amdgcn_mfma_f32_16x16x32_bf16(
                af2[kc], wb2[nt * 3 + kc], acc2[nt], 0, 0, 0);

    float part[4] = {0.f, 0.f, 0.f, 0.f};
    #pragma unroll
    for (int nt = 0; nt < 3; ++nt) {
        #pragma unroll
        for (int rg = 0; rg < 4; ++rg)
            part[rg] += sigm_(acc2[nt][rg] + b2v[nt]) * w3v[nt];
    }
    #pragma unroll
    for (int off = 1; off < 16; off <<= 1) {
        #pragma unroll
        for (int rg = 0; rg < 4; ++rg)
            part[rg] += __shfl_xor(part[rg], off, 64);
    }
    #pragma unroll
    for (int rg = 0; rg < 4; ++rg) score[rg] = part[rg];
}

// ---------------------------------------------------------------------------
// DIN-0 + fused reduceK (round-9 proven shape, best measured 53.5 us).
// Grid 2048 x 320 threads, tile = 80 rows = 8 bs.
// ---------------------------------------------------------------------------
__global__ __launch_bounds__(320) void k_din0(
    const int* __restrict__ click_his, const int* __restrict__ unclick_his,
    const float* __restrict__ click_mask, const float* __restrict__ unclick_mask,
    const float* __restrict__ emb, const __bf16* __restrict__ Wt,
    const float* __restrict__ b1, const float* __restrict__ b2,
    const float* __restrict__ W3, const float* __restrict__ b3,
    float* __restrict__ unatt, float* __restrict__ coef)
{
    __shared__ __align__(16) __bf16 sW1[80 * XSTR];        // 32000 B
    __shared__ __align__(16) __bf16 sH1[5 * 16 * H1STR];   // 16640 B
    __shared__ float ssc[80];

    const int t = threadIdx.x;
    const int wave = t >> 6, lane = t & 63;
    const int quad = lane >> 4, l15 = lane & 15;

    {
        const uint4* s1 = (const uint4*)Wt;
        uint4* d1 = (uint4*)sW1;
        for (int e = t; e < W1ELTS / 8; e += 320) d1[e] = s1[e];
    }

    bfrag wb2[9];
    float b1v[5], b2v[3], w3v[3];
    {
        const __bf16* w2g = Wt + W1ELTS;
        #pragma unroll
        for (int nt = 0; nt < 3; ++nt)
            #pragma unroll
            for (int kc = 0; kc < 3; ++kc)
                wb2[nt * 3 + kc] = *(const bfrag*)(w2g + (nt * 16 + l15) * H1STR + kc * 32 + quad * 8);
        #pragma unroll
        for (int nt = 0; nt < 5; ++nt) b1v[nt] = b1[nt * 16 + l15];
        #pragma unroll
        for (int nt = 0; nt < 3; ++nt) {
            const int n = nt * 16 + l15;
            b2v[nt] = (n < 40) ? b2[n] : 0.0f;
            w3v[nt] = (n < 40) ? W3[n] : 0.0f;
        }
    }
    const float b3v = b3[0];

    const int row = 16 * wave + l15;                 // 0..79
    const int m   = blockIdx.x * 80 + row;
    const int bs  = blockIdx.x * 8 + row / 10;
    float qv[16], fv[16];
    {
        const float* qp = emb + (size_t)click_his[bs] * DD;
        const float* fp = emb + (size_t)unclick_his[m] * DD;
        const float qs = click_mask[bs], fs = unclick_mask[m];
        const int c = quad * 8;
        *(float4*)(qv + 0)  = *(const float4*)(qp + c);
        *(float4*)(qv + 4)  = *(const float4*)(qp + c + 4);
        *(float4*)(qv + 8)  = *(const float4*)(qp + 32 + c);
        *(float4*)(qv + 12) = *(const float4*)(qp + 32 + c + 4);
        *(float4*)(fv + 0)  = *(const float4*)(fp + c);
        *(float4*)(fv + 4)  = *(const float4*)(fp + c + 4);
        *(float4*)(fv + 8)  = *(const float4*)(fp + 32 + c);
        *(float4*)(fv + 12) = *(const float4*)(fp + 32 + c + 4);
        #pragma unroll
        for (int i = 0; i < 16; ++i) { qv[i] *= qs; fv[i] *= fs; }
    }
    __syncthreads();   // weights staged

    float score[4];
    mlp_core(qv, fv, sW1, sH1 + wave * 16 * H1STR, wb2, b1v, b2v, w3v, quad, l15, score);

    if (l15 == 0) {
        #pragma unroll
        for (int rg = 0; rg < 4; ++rg) {
            const int r2 = 16 * wave + quad * 4 + rg;
            const int m2 = blockIdx.x * 80 + r2;
            ssc[r2] = (unclick_mask[m2] == 1.0f) ? (score[rg] + b3v) : BIG_NEG_F;
        }
    }
    __syncthreads();   // ssc ready

    for (int j = wave; j < 8; j += 5) {
        const int bsj = blockIdx.x * 8 + j;
        float a[KK];
        float mx = -INFINITY;
        #pragma unroll
        for (int k = 0; k < KK; ++k) { a[k] = ssc[j * KK + k]; mx = fmaxf(mx, a[k]); }
        float sum = 0.0f;
        #pragma unroll
        for (int k = 0; k < KK; ++k) { a[k] = __expf(a[k] - mx); sum += a[k]; }
        const float inv = 1.0f / sum;
        float acc3 = 0.0f;
        #pragma unroll
        for (int k = 0; k < KK; ++k) {
            const int off = bsj * KK + k;
            acc3 += a[k] * (emb[(size_t)unclick_his[off] * DD + lane] * unclick_mask[off]);
        }
        acc3 *= inv;
        unatt[(size_t)bsj * DD + lane] = acc3;
        const float qv2 = emb[(size_t)click_his[bsj] * DD + lane] * click_mask[bsj];
        float dp = acc3 * qv2, nq = qv2 * qv2;
        #pragma unroll
        for (int o = 32; o > 0; o >>= 1) {
            dp += __shfl_down(dp, o, 64);
            nq += __shfl_down(nq, o, 64);
        }
        if (lane == 0) coef[bsj] = 1.0f + dp / (nq + 1e-12f);
    }
}

// ---------------------------------------------------------------------------
// Fused DIN-1/2 + attend + head. One block per b, 512 threads (8 waves).
// Scores live entirely in LDS; head scratch aliases sH1 after scores.
// ---------------------------------------------------------------------------
__global__ __launch_bounds__(512) void k_fused(
    const int* __restrict__ mid, const int* __restrict__ click_his,
    const float* __restrict__ click_mask,
    const float* __restrict__ emb, const float* __restrict__ unatt,
    const float* __restrict__ coef, const __bf16* __restrict__ Wt,
    const float* __restrict__ cb1, const float* __restrict__ cb2,
    const float* __restrict__ cW3, const float* __restrict__ cb3,
    const float* __restrict__ ub1, const float* __restrict__ ub2,
    const float* __restrict__ uW3, const float* __restrict__ ub3,
    const float* __restrict__ bn_g, const float* __restrict__ bn_b,
    const float* __restrict__ bn_m, const float* __restrict__ bn_v,
    const float* __restrict__ fW1, const float* __restrict__ fb1, const float* __restrict__ a1,
    const float* __restrict__ fW2, const float* __restrict__ fb2, const float* __restrict__ a2,
    const float* __restrict__ fW3, const float* __restrict__ fb3,
    float* __restrict__ out)
{
    __shared__ __align__(16) __bf16 sW1[80 * XSTR];        // 32000 B
    __shared__ __align__(16) __bf16 sH1[8][16 * H1STR];    // 26624 B (also head scratch)
    __shared__ float ssc[2][SS];                           // 2048 B

    const int b = blockIdx.x, t = threadIdx.x;
    const int wave = t >> 6, lane = t & 63;
    const int quad = lane >> 4, l15 = lane & 15;
    const int c = quad * 8;

    // head scratch aliases sH1 (free after the scores phase)
    float* scratch = (float*)&sH1[0][0];
    float* part = scratch;           // [8][72]
    float* xv   = scratch + 576;     // [192]
    float* ph1  = scratch + 768;     // [2][200]
    float* h1s  = scratch + 1168;    // [200]
    float* ph2  = scratch + 1368;    // [5][80]
    float* h2s  = scratch + 1768;    // [80]
    float* smax = scratch + 1848;    // [8]
    float* ssum = scratch + 1856;    // [8]
    float* red2 = scratch + 1864;    // [2]

    // item (q) A-slice — same row for every MLP row in this block
    const float* qp = emb + (size_t)mid[b] * DD;
    float qv[16];
    *(float4*)(qv + 0)  = *(const float4*)(qp + c);
    *(float4*)(qv + 4)  = *(const float4*)(qp + c + 4);
    *(float4*)(qv + 8)  = *(const float4*)(qp + 32 + c);
    *(float4*)(qv + 12) = *(const float4*)(qp + 32 + c + 4);

    // ---- scores: mode 0 = c (click*coef), mode 1 = u (un_att) ----
    #pragma unroll 1
    for (int mode = 0; mode < 2; ++mode) {
        const __bf16* wreg = Wt + (mode + 1) * WREG;
        {
            const uint4* s1 = (const uint4*)wreg;
            uint4* d1 = (uint4*)sW1;
            for (int e = t; e < W1ELTS / 8; e += 512) d1[e] = s1[e];
        }
        bfrag wb2[9];
        float b1v[5], b2v[3], w3v[3];
        {
            const float* b1 = mode ? ub1 : cb1;
            const float* b2 = mode ? ub2 : cb2;
            const float* W3 = mode ? uW3 : cW3;
            const __bf16* w2g = wreg + W1ELTS;
            #pragma unroll
            for (int nt = 0; nt < 3; ++nt)
                #pragma unroll
                for (int kc = 0; kc < 3; ++kc)
                    wb2[nt * 3 + kc] = *(const bfrag*)(w2g + (nt * 16 + l15) * H1STR + kc * 32 + quad * 8);
            #pragma unroll
            for (int nt = 0; nt < 5; ++nt) b1v[nt] = b1[nt * 16 + l15];
            #pragma unroll
            for (int nt = 0; nt < 3; ++nt) {
                const int n = nt * 16 + l15;
                b2v[nt] = (n < 40) ? b2[n] : 0.0f;
                w3v[nt] = (n < 40) ? W3[n] : 0.0f;
            }
        }
        const float b3v = (mode ? ub3 : cb3)[0];
        __syncthreads();   // weights staged

        #pragma unroll 1
        for (int tt = 0; tt < 2; ++tt) {
            const int row = wave * 32 + tt * 16 + l15;   // 0..255
            const int m   = b * SS + row;
            float fv[16];
            {
                const float* fp; float fs;
                if (mode == 0) { fp = emb + (size_t)click_his[m] * DD; fs = click_mask[m] * coef[m]; }
                else           { fp = unatt + (size_t)m * DD; fs = 1.0f; }
                *(float4*)(fv + 0)  = *(const float4*)(fp + c);
                *(float4*)(fv + 4)  = *(const float4*)(fp + c + 4);
                *(float4*)(fv + 8)  = *(const float4*)(fp + 32 + c);
                *(float4*)(fv + 12) = *(const float4*)(fp + 32 + c + 4);
                #pragma unroll
                for (int i = 0; i < 16; ++i) fv[i] *= fs;
            }
            float score[4];
            mlp_core(qv, fv, sW1, sH1[wave], wb2, b1v, b2v, w3v, quad, l15, score);
            if (l15 == 0) {
                #pragma unroll
                for (int rg = 0; rg < 4; ++rg) {
                    const int r2 = wave * 32 + tt * 16 + quad * 4 + rg;
                    const int m2 = b * SS + r2;
                    ssc[mode][r2] = (click_mask[m2] == 1.0f) ? (score[rg] + b3v) : BIG_NEG_F;
                }
            }
        }
        __syncthreads();   // all scores in LDS; sW1/sH1 free for next mode
    }

    // ---- item row into xv (scratch now safe) ----
    if (t < DD) xv[t] = qp[t];

    // ---- attend: softmax over S=256 + weighted fact sums, per ty ----
    #pragma unroll 1
    for (int ty = 0; ty < 2; ++ty) {
        const float sc = (lane < 32) ? ssc[ty][wave * 32 + lane] : -INFINITY;
        float mloc = sc;
        #pragma unroll
        for (int o = 32; o > 0; o >>= 1) mloc = fmaxf(mloc, __shfl_xor(mloc, o, 64));
        if (lane == 0) smax[wave] = mloc;
        __syncthreads();
        float mt = smax[0];
        #pragma unroll
        for (int i = 1; i < 8; ++i) mt = fmaxf(mt, smax[i]);
        const float e = (lane < 32) ? __expf(sc - mt) : 0.0f;
        float sloc = e;
        #pragma unroll
        for (int o = 32; o > 0; o >>= 1) sloc += __shfl_xor(sloc, o, 64);
        if (lane == 0) ssum[wave] = sloc;
        if (lane < 32) ssc[ty][wave * 32 + lane] = e;   // overwrite score with exp
        __syncthreads();
        float den = 0.0f;
        #pragma unroll
        for (int i = 0; i < 8; ++i) den += ssum[i];
        const float inv = 1.0f / den;

        float acc = 0.0f;
        #pragma unroll 4
        for (int i = 0; i < 32; ++i) {
            const int s2 = wave * 32 + i;
            const int bs = b * SS + s2;
            const float fvv = ty ? unatt[(size_t)bs * DD + lane]
                                 : emb[(size_t)click_his[bs] * DD + lane] * click_mask[bs] * coef[bs];
            acc += ssc[ty][s2] * fvv;
        }
        part[wave * 72 + lane] = acc * inv;
        __syncthreads();
        if (t < DD) {
            float v = 0.0f;
            #pragma unroll
            for (int w2 = 0; w2 < 8; ++w2) v += part[w2 * 72 + t];
            xv[DD + ty * DD + t] = v;
        }
        __syncthreads();
    }

    // ---- BN + head MLP + softmax ----
    if (t < FF) xv[t] = (xv[t] - bn_m[t]) * rsqrtf(bn_v[t] + 1e-3f) * bn_g[t] + bn_b[t];
    __syncthreads();

    if (t < 400) {
        const int n = t % FH1, cc = t / FH1;   // 2 chunks of k=96
        float p = 0.0f;
        #pragma unroll 8
        for (int i = cc * 96; i < cc * 96 + 96; ++i) p += xv[i] * fW1[i * FH1 + n];
        ph1[cc * FH1 + n] = p;
    }
    __syncthreads();
    if (t < FH1) {
        const float a = ph1[t] + ph1[FH1 + t] + fb1[t];
        h1s[t] = fmaxf(a, 0.0f) + a1[t] * fminf(a, 0.0f);
    }
    __syncthreads();

    if (t < 400) {
        const int n = t % FH2, cc = t / FH2;   // 5 chunks of k=40
        float p = 0.0f;
        #pragma unroll 8
        for (int i = cc * 40; i < cc * 40 + 40; ++i) p += h1s[i] * fW2[i * FH2 + n];
        ph2[cc * FH2 + n] = p;
    }
    __syncthreads();
    if (t < FH2) {
        float a = fb2[t];
        #pragma unroll
        for (int cc = 0; cc < 5; ++cc) a += ph2[cc * FH2 + t];
        h2s[t] = fmaxf(a, 0.0f) + a2[t] * fminf(a, 0.0f);
    }
    __syncthreads();

    if (t < 128) {
        const int o = t >> 6;
        float p = h2s[lane] * fW3[lane * 2 + o];
        if (lane < 16) p += h2s[64 + lane] * fW3[(64 + lane) * 2 + o];
        #pragma unroll
        for (int off = 32; off > 0; off >>= 1) p += __shfl_down(p, off, 64);
        if (lane == 0) red2[o] = p + fb3[o];
    }
    __syncthreads();
    if (t == 0) {
        const float l0 = red2[0], l1 = red2[1];
        const float mx = fmaxf(l0, l1);
        const float e0 = __expf(l0 - mx), e1 = __expf(l1 - mx);
        const float invs = 1.0f / (e0 + e1);
        out[b * 2 + 0] = e0 * invs + 1e-8f;
        out[b * 2 + 1] = e1 * invs + 1e-8f;
    }
}

// ---------------------------------------------------------------------------
extern "C" void kernel_launch(void* const* d_in, const int* in_sizes, int n_in,
                              void* d_out, int out_size, void* d_ws, size_t ws_size,
                              hipStream_t stream) {
    const int*   mid          = (const int*)d_in[0];
    const int*   click_his    = (const int*)d_in[1];
    const int*   unclick_his  = (const int*)d_in[2];
    const float* click_mask   = (const float*)d_in[3];
    const float* unclick_mask = (const float*)d_in[4];
    const float* emb          = (const float*)d_in[5];
    const float* sW1 = (const float*)d_in[6];  const float* sb1 = (const float*)d_in[7];
    const float* sW2 = (const float*)d_in[8];  const float* sb2 = (const float*)d_in[9];
    const float* sW3 = (const float*)d_in[10]; const float* sb3 = (const float*)d_in[11];
    const float* cW1 = (const float*)d_in[12]; const float* cb1 = (const float*)d_in[13];
    const float* cW2 = (const float*)d_in[14]; const float* cb2 = (const float*)d_in[15];
    const float* cW3 = (const float*)d_in[16]; const float* cb3 = (const float*)d_in[17];
    const float* uW1 = (const float*)d_in[18]; const float* ub1 = (const float*)d_in[19];
    const float* uW2 = (const float*)d_in[20]; const float* ub2 = (const float*)d_in[21];
    const float* uW3 = (const float*)d_in[22]; const float* ub3 = (const float*)d_in[23];
    const float* bn_g = (const float*)d_in[24]; const float* bn_b = (const float*)d_in[25];
    const float* bn_m = (const float*)d_in[26]; const float* bn_v = (const float*)d_in[27];
    const float* fW1 = (const float*)d_in[28]; const float* fb1 = (const float*)d_in[29];
    const float* a1  = (const float*)d_in[30];
    const float* fW2 = (const float*)d_in[31]; const float* fb2 = (const float*)d_in[32];
    const float* a2  = (const float*)d_in[33];
    const float* fW3 = (const float*)d_in[34]; const float* fb3 = (const float*)d_in[35];

    float* out = (float*)d_out;

    // Workspace layout (bytes, 16B-aligned)
    char* w = (char*)d_ws;
    __bf16* Wt   = (__bf16*)(w + 0);       // 125952 B
    float* coef  = (float*)(w + 125952);   // 65536 B
    float* unatt = (float*)(w + 191488);   // 4194304 B

    hipLaunchKernelGGL(k_prep, dim3(3, 40), dim3(256), 0, stream,
        sW1, sW2, cW1, cW2, uW1, uW2, Wt);

    hipLaunchKernelGGL(k_din0, dim3(2048), dim3(320), 0, stream,
        click_his, unclick_his, click_mask, unclick_mask, emb, Wt,
        sb1, sb2, sW3, sb3, unatt, coef);

    hipLaunchKernelGGL(k_fused, dim3(BB), dim3(512), 0, stream,
        mid, click_his, click_mask, emb, unatt, coef, Wt,
        cb1, cb2, cW3, cb3, ub1, ub2, uW3, ub3,
        bn_g, bn_b, bn_m, bn_v, fW1, fb1, a1, fW2, fb2, a2, fW3, fb3, out);
}

// Round 13
// 219.636 us; speedup vs baseline: 1.0247x; 1.0200x over previous
//
#include <hip/hip_runtime.h>
#include <hip/hip_bf16.h>
#include <math.h>

// Problem constants
#define BB 64      // batch
#define SS 256     // click seq len
#define KK 10      // unclick per click
#define DD 64      // emb dim
#define FF 192     // 3*D
#define FH1 200
#define FH2 80
#define BIG_NEG_F (-4294967295.0f)

// LDS strides
#define XSTR 200   // W1t row stride in bf16 (192 + 8 pad)
#define H1STR 104  // H1 / W2t row stride in bf16 (96 + 8 pad)

// folded-weight region per MLP (bf16 elements)
#define W1ELTS (80 * XSTR)          // 16000
#define W2ELTS (48 * H1STR)         // 4992
#define WREG   (W1ELTS + W2ELTS)    // 20992 bf16 = 41984 B

typedef __bf16 bfrag __attribute__((ext_vector_type(8)));
typedef float f32x4 __attribute__((ext_vector_type(4)));

__device__ __forceinline__ float sigm_(float x) { return 1.0f / (1.0f + __expf(-x)); }

// ---------------------------------------------------------------------------
// Prep: fold W1 (256x80) -> W1t[n][k]; pad cols zeroed; W2 -> W2t[n][k].
// ---------------------------------------------------------------------------
__global__ __launch_bounds__(256) void k_prep(
    const float* __restrict__ sW1, const float* __restrict__ sW2,
    const float* __restrict__ cW1, const float* __restrict__ cW2,
    const float* __restrict__ uW1, const float* __restrict__ uW2,
    __bf16* __restrict__ Wt)
{
    const int p = blockIdx.x, g = blockIdx.y;
    const float* W1 = (p == 0) ? sW1 : (p == 1) ? cW1 : uW1;   // [256][80]
    const float* W2 = (p == 0) ? sW2 : (p == 1) ? cW2 : uW2;   // [80][40]
    __bf16* o1 = Wt + p * WREG;
    __bf16* o2 = o1 + W1ELTS;
    for (int e = g * 256 + threadIdx.x; e < 200 * 80; e += 10240) {
        const int k = e / 80, n = e % 80;
        float v;
        if (k < 64)       v = W1[k * 80 + n] + W1[(k + 128) * 80 + n];
        else if (k < 128) v = W1[k * 80 + n] - W1[(k + 64) * 80 + n];
        else if (k < 192) v = W1[(k + 64) * 80 + n];
        else              v = 0.0f;
        o1[n * XSTR + k] = (__bf16)v;
    }
    for (int e = g * 256 + threadIdx.x; e < W2ELTS; e += 10240) {
        const int n = e / H1STR, k = e % H1STR;
        o2[e] = (__bf16)((n < 40 && k < 80) ? W2[k * 40 + n] : 0.0f);
    }
}

// ---------------------------------------------------------------------------
// Wave-level MLP core. score[rg] valid on l15==0 lanes.
// ---------------------------------------------------------------------------
__device__ __forceinline__ void mlp_core(
    const float* qv, const float* fv,
    const __bf16* __restrict__ sW1, __bf16* __restrict__ sH1w,
    const bfrag* wb2, const float* b1v, const float* b2v, const float* w3v,
    int quad, int l15, float* score)
{
    bfrag af[6];
    #pragma unroll
    for (int j = 0; j < 8; ++j) {
        af[0][j] = (__bf16)qv[j];
        af[1][j] = (__bf16)qv[8 + j];
        af[2][j] = (__bf16)fv[j];
        af[3][j] = (__bf16)fv[8 + j];
        af[4][j] = (__bf16)(qv[j] * fv[j]);
        af[5][j] = (__bf16)(qv[8 + j] * fv[8 + j]);
    }

    f32x4 acc[5];
    #pragma unroll
    for (int nt = 0; nt < 5; ++nt) acc[nt] = (f32x4){0.f, 0.f, 0.f, 0.f};
    {
        const __bf16* wbase = sW1 + l15 * XSTR + quad * 8;
        #pragma unroll
        for (int nt = 0; nt < 5; ++nt) {
            const __bf16* wp = wbase + nt * 16 * XSTR;
            #pragma unroll
            for (int kc = 0; kc < 6; ++kc)
                acc[nt] = __builtin_amdgcn_mfma_f32_16x16x32_bf16(
                    af[kc], *(const bfrag*)(wp + kc * 32), acc[nt], 0, 0, 0);
        }
    }

    #pragma unroll
    for (int nt = 0; nt < 5; ++nt) {
        #pragma unroll
        for (int rg = 0; rg < 4; ++rg)
            sH1w[(quad * 4 + rg) * H1STR + nt * 16 + l15] =
                (__bf16)sigm_(acc[nt][rg] + b1v[nt]);
    }
    #pragma unroll
    for (int rg = 0; rg < 4; ++rg)
        sH1w[(quad * 4 + rg) * H1STR + 80 + l15] = (__bf16)0.0f;

    bfrag af2[3];
    {
        const __bf16* hrow = sH1w + l15 * H1STR + quad * 8;
        #pragma unroll
        for (int kc = 0; kc < 3; ++kc) af2[kc] = *(const bfrag*)(hrow + kc * 32);
    }
    f32x4 acc2[3];
    #pragma unroll
    for (int nt = 0; nt < 3; ++nt) acc2[nt] = (f32x4){0.f, 0.f, 0.f, 0.f};
    #pragma unroll
    for (int nt = 0; nt < 3; ++nt)
        #pragma unroll
        for (int kc = 0; kc < 3; ++kc)
            acc2[nt] = __builtin_amdgcn_mfma_f32_16x16x32_bf16(
                af2[kc], wb2[nt * 3 + kc], acc2[nt], 0, 0, 0);

    float part[4] = {0.f, 0.f, 0.f, 0.f};
    #pragma unroll
    for (int nt = 0; nt < 3; ++nt) {
        #pragma unroll
        for (int rg = 0; rg < 4; ++rg)
            part[rg] += sigm_(acc2[nt][rg] + b2v[nt]) * w3v[nt];
    }
    #pragma unroll
    for (int off = 1; off < 16; off <<= 1) {
        #pragma unroll
        for (int rg = 0; rg < 4; ++rg)
            part[rg] += __shfl_xor(part[rg], off, 64);
    }
    #pragma unroll
    for (int rg = 0; rg < 4; ++rg) score[rg] = part[rg];
}

// ---------------------------------------------------------------------------
// DIN-0 + fused reduceK. 640 threads (10 waves), 160 rows/block, grid 1024.
// Same per-wave code as the proven round-9 shape; 2 blocks/CU = 20 waves/CU,
// half the weight-staging generations.
// ---------------------------------------------------------------------------
__global__ __launch_bounds__(640) void k_din0(
    const int* __restrict__ click_his, const int* __restrict__ unclick_his,
    const float* __restrict__ click_mask, const float* __restrict__ unclick_mask,
    const float* __restrict__ emb, const __bf16* __restrict__ Wt,
    const float* __restrict__ b1, const float* __restrict__ b2,
    const float* __restrict__ W3, const float* __restrict__ b3,
    float* __restrict__ unatt, float* __restrict__ coef)
{
    __shared__ __align__(16) __bf16 sW1[80 * XSTR];         // 32000 B
    __shared__ __align__(16) __bf16 sH1[10 * 16 * H1STR];   // 33280 B
    __shared__ float ssc[160];                              // 640 B

    const int t = threadIdx.x;
    const int wave = t >> 6, lane = t & 63;
    const int quad = lane >> 4, l15 = lane & 15;

    {
        const uint4* s1 = (const uint4*)Wt;
        uint4* d1 = (uint4*)sW1;
        for (int e = t; e < W1ELTS / 8; e += 640) d1[e] = s1[e];
    }

    bfrag wb2[9];
    float b1v[5], b2v[3], w3v[3];
    {
        const __bf16* w2g = Wt + W1ELTS;
        #pragma unroll
        for (int nt = 0; nt < 3; ++nt)
            #pragma unroll
            for (int kc = 0; kc < 3; ++kc)
                wb2[nt * 3 + kc] = *(const bfrag*)(w2g + (nt * 16 + l15) * H1STR + kc * 32 + quad * 8);
        #pragma unroll
        for (int nt = 0; nt < 5; ++nt) b1v[nt] = b1[nt * 16 + l15];
        #pragma unroll
        for (int nt = 0; nt < 3; ++nt) {
            const int n = nt * 16 + l15;
            b2v[nt] = (n < 40) ? b2[n] : 0.0f;
            w3v[nt] = (n < 40) ? W3[n] : 0.0f;
        }
    }
    const float b3v = b3[0];

    const int row = 16 * wave + l15;                 // 0..159
    const int m   = blockIdx.x * 160 + row;
    const int bs  = m / 10;
    float qv[16], fv[16];
    {
        const float* qp = emb + (size_t)click_his[bs] * DD;
        const float* fp = emb + (size_t)unclick_his[m] * DD;
        const float qs = click_mask[bs], fs = unclick_mask[m];
        const int c = quad * 8;
        *(float4*)(qv + 0)  = *(const float4*)(qp + c);
        *(float4*)(qv + 4)  = *(const float4*)(qp + c + 4);
        *(float4*)(qv + 8)  = *(const float4*)(qp + 32 + c);
        *(float4*)(qv + 12) = *(const float4*)(qp + 32 + c + 4);
        *(float4*)(fv + 0)  = *(const float4*)(fp + c);
        *(float4*)(fv + 4)  = *(const float4*)(fp + c + 4);
        *(float4*)(fv + 8)  = *(const float4*)(fp + 32 + c);
        *(float4*)(fv + 12) = *(const float4*)(fp + 32 + c + 4);
        #pragma unroll
        for (int i = 0; i < 16; ++i) { qv[i] *= qs; fv[i] *= fs; }
    }
    __syncthreads();   // weights staged

    float score[4];
    mlp_core(qv, fv, sW1, sH1 + wave * 16 * H1STR, wb2, b1v, b2v, w3v, quad, l15, score);

    if (l15 == 0) {
        #pragma unroll
        for (int rg = 0; rg < 4; ++rg) {
            const int r2 = 16 * wave + quad * 4 + rg;
            const int m2 = blockIdx.x * 160 + r2;
            ssc[r2] = (unclick_mask[m2] == 1.0f) ? (score[rg] + b3v) : BIG_NEG_F;
        }
    }
    __syncthreads();   // ssc ready

    // reduceK: 16 bs over 10 waves (waves 0-5 do 2, waves 6-9 do 1)
    for (int j = wave; j < 16; j += 10) {
        const int bsj = blockIdx.x * 16 + j;
        float a[KK];
        float mx = -INFINITY;
        #pragma unroll
        for (int k = 0; k < KK; ++k) { a[k] = ssc[j * KK + k]; mx = fmaxf(mx, a[k]); }
        float sum = 0.0f;
        #pragma unroll
        for (int k = 0; k < KK; ++k) { a[k] = __expf(a[k] - mx); sum += a[k]; }
        const float inv = 1.0f / sum;
        float acc3 = 0.0f;
        #pragma unroll
        for (int k = 0; k < KK; ++k) {
            const int off = bsj * KK + k;
            acc3 += a[k] * (emb[(size_t)unclick_his[off] * DD + lane] * unclick_mask[off]);
        }
        acc3 *= inv;
        unatt[(size_t)bsj * DD + lane] = acc3;
        const float qv2 = emb[(size_t)click_his[bsj] * DD + lane] * click_mask[bsj];
        float dp = acc3 * qv2, nq = qv2 * qv2;
        #pragma unroll
        for (int o = 32; o > 0; o >>= 1) {
            dp += __shfl_down(dp, o, 64);
            nq += __shfl_down(nq, o, 64);
        }
        if (lane == 0) coef[bsj] = 1.0f + dp / (nq + 1e-12f);
    }
}

// ---------------------------------------------------------------------------
// Fused DIN-1/2 + attend + head. One block per b, 1024 threads (16 waves):
// each mode's 256 scores computed in ONE wave-parallel pass; attend runs
// both types concurrently; head k-split. Head scratch aliases sH1.
// ---------------------------------------------------------------------------
__global__ __launch_bounds__(1024) void k_fused(
    const int* __restrict__ mid, const int* __restrict__ click_his,
    const float* __restrict__ click_mask,
    const float* __restrict__ emb, const float* __restrict__ unatt,
    const float* __restrict__ coef, const __bf16* __restrict__ Wt,
    const float* __restrict__ cb1, const float* __restrict__ cb2,
    const float* __restrict__ cW3, const float* __restrict__ cb3,
    const float* __restrict__ ub1, const float* __restrict__ ub2,
    const float* __restrict__ uW3, const float* __restrict__ ub3,
    const float* __restrict__ bn_g, const float* __restrict__ bn_b,
    const float* __restrict__ bn_m, const float* __restrict__ bn_v,
    const float* __restrict__ fW1, const float* __restrict__ fb1, const float* __restrict__ a1,
    const float* __restrict__ fW2, const float* __restrict__ fb2, const float* __restrict__ a2,
    const float* __restrict__ fW3, const float* __restrict__ fb3,
    float* __restrict__ out)
{
    __shared__ __align__(16) __bf16 sW1[80 * XSTR];         // 32000 B
    __shared__ __align__(16) __bf16 sH1[16][16 * H1STR];    // 53248 B (also head scratch)
    __shared__ float ssc[2][SS];                            // 2048 B

    const int b = blockIdx.x, t = threadIdx.x;
    const int wave = t >> 6, lane = t & 63;
    const int quad = lane >> 4, l15 = lane & 15;
    const int c = quad * 8;

    // head scratch aliases sH1 (free after the scores phase)
    float* scratch = (float*)&sH1[0][0];
    float* part = scratch;           // [16][72] = 1152
    float* xv   = scratch + 1152;    // [192]
    float* ph1  = scratch + 1344;    // [4][200]
    float* h1s  = scratch + 2144;    // [200]
    float* ph2  = scratch + 2344;    // [8][80]
    float* h2s  = scratch + 2984;    // [80]
    float* smax = scratch + 3064;    // [16]
    float* ssum = scratch + 3080;    // [16]
    float* red2 = scratch + 3096;    // [2]

    const float* qp = emb + (size_t)mid[b] * DD;
    float qv[16];
    *(float4*)(qv + 0)  = *(const float4*)(qp + c);
    *(float4*)(qv + 4)  = *(const float4*)(qp + c + 4);
    *(float4*)(qv + 8)  = *(const float4*)(qp + 32 + c);
    *(float4*)(qv + 12) = *(const float4*)(qp + 32 + c + 4);

    // ---- scores: mode 0 = c (click*coef), mode 1 = u (un_att) ----
    #pragma unroll 1
    for (int mode = 0; mode < 2; ++mode) {
        const __bf16* wreg = Wt + (mode + 1) * WREG;
        {
            const uint4* s1 = (const uint4*)wreg;
            uint4* d1 = (uint4*)sW1;
            for (int e = t; e < W1ELTS / 8; e += 1024) d1[e] = s1[e];
        }
        bfrag wb2[9];
        float b1v[5], b2v[3], w3v[3];
        {
            const float* b1 = mode ? ub1 : cb1;
            const float* b2 = mode ? ub2 : cb2;
            const float* W3 = mode ? uW3 : cW3;
            const __bf16* w2g = wreg + W1ELTS;
            #pragma unroll
            for (int nt = 0; nt < 3; ++nt)
                #pragma unroll
                for (int kc = 0; kc < 3; ++kc)
                    wb2[nt * 3 + kc] = *(const bfrag*)(w2g + (nt * 16 + l15) * H1STR + kc * 32 + quad * 8);
            #pragma unroll
            for (int nt = 0; nt < 5; ++nt) b1v[nt] = b1[nt * 16 + l15];
            #pragma unroll
            for (int nt = 0; nt < 3; ++nt) {
                const int n = nt * 16 + l15;
                b2v[nt] = (n < 40) ? b2[n] : 0.0f;
                w3v[nt] = (n < 40) ? W3[n] : 0.0f;
            }
        }
        const float b3v = (mode ? ub3 : cb3)[0];
        __syncthreads();   // weights staged

        {
            const int row = wave * 16 + l15;   // 0..255 — whole pass in one step
            const int m   = b * SS + row;
            float fv[16];
            {
                const float* fp; float fs;
                if (mode == 0) { fp = emb + (size_t)click_his[m] * DD; fs = click_mask[m] * coef[m]; }
                else           { fp = unatt + (size_t)m * DD; fs = 1.0f; }
                *(float4*)(fv + 0)  = *(const float4*)(fp + c);
                *(float4*)(fv + 4)  = *(const float4*)(fp + c + 4);
                *(float4*)(fv + 8)  = *(const float4*)(fp + 32 + c);
                *(float4*)(fv + 12) = *(const float4*)(fp + 32 + c + 4);
                #pragma unroll
                for (int i = 0; i < 16; ++i) fv[i] *= fs;
            }
            float score[4];
            mlp_core(qv, fv, sW1, sH1[wave], wb2, b1v, b2v, w3v, quad, l15, score);
            if (l15 == 0) {
                #pragma unroll
                for (int rg = 0; rg < 4; ++rg) {
                    const int r2 = wave * 16 + quad * 4 + rg;
                    const int m2 = b * SS + r2;
                    ssc[mode][r2] = (click_mask[m2] == 1.0f) ? (score[rg] + b3v) : BIG_NEG_F;
                }
            }
        }
        __syncthreads();   // all scores in LDS; sW1/sH1 free for next mode
    }

    // ---- item row into xv (scratch now safe) ----
    if (t < DD) xv[t] = qp[t];

    // ---- attend: both types concurrently (waves 0-7: ty=0, 8-15: ty=1) ----
    const int ty = wave >> 3, w8 = wave & 7;
    const int s0 = w8 * 32;
    {
        const float sc = (lane < 32) ? ssc[ty][s0 + lane] : -INFINITY;
        float mloc = sc;
        #pragma unroll
        for (int o = 32; o > 0; o >>= 1) mloc = fmaxf(mloc, __shfl_xor(mloc, o, 64));
        if (lane == 0) smax[wave] = mloc;
        __syncthreads();
        float mt = smax[ty * 8];
        #pragma unroll
        for (int i = 1; i < 8; ++i) mt = fmaxf(mt, smax[ty * 8 + i]);
        const float e = (lane < 32) ? __expf(sc - mt) : 0.0f;
        if (lane < 32) ssc[ty][s0 + lane] = e;
        float sloc = e;
        #pragma unroll
        for (int o = 32; o > 0; o >>= 1) sloc += __shfl_xor(sloc, o, 64);
        if (lane == 0) ssum[wave] = sloc;
        __syncthreads();
        float den = 0.0f;
        #pragma unroll
        for (int i = 0; i < 8; ++i) den += ssum[ty * 8 + i];
        const float inv = 1.0f / den;

        float acc = 0.0f;
        #pragma unroll 4
        for (int i = 0; i < 32; ++i) {
            const int s2 = s0 + i;
            const int bs = b * SS + s2;
            const float fvv = ty ? unatt[(size_t)bs * DD + lane]
                                 : emb[(size_t)click_his[bs] * DD + lane] * click_mask[bs] * coef[bs];
            acc += ssc[ty][s2] * fvv;
        }
        part[wave * 72 + lane] = acc * inv;
        __syncthreads();
        if (t < 128) {
            const int tt = t >> 6, d = t & 63;
            float v = 0.0f;
            #pragma unroll
            for (int i = 0; i < 8; ++i) v += part[(tt * 8 + i) * 72 + d];
            xv[DD + tt * DD + d] = v;
        }
        __syncthreads();
    }

    // ---- BN + head MLP + softmax ----
    if (t < FF) xv[t] = (xv[t] - bn_m[t]) * rsqrtf(bn_v[t] + 1e-3f) * bn_g[t] + bn_b[t];
    __syncthreads();

    if (t < 800) {
        const int n = t % FH1, cc = t / FH1;   // 4 chunks of k=48
        float p = 0.0f;
        #pragma unroll 8
        for (int i = cc * 48; i < cc * 48 + 48; ++i) p += xv[i] * fW1[i * FH1 + n];
        ph1[cc * FH1 + n] = p;
    }
    __syncthreads();
    if (t < FH1) {
        const float a = ph1[t] + ph1[FH1 + t] + ph1[2 * FH1 + t] + ph1[3 * FH1 + t] + fb1[t];
        h1s[t] = fmaxf(a, 0.0f) + a1[t] * fminf(a, 0.0f);
    }
    __syncthreads();

    if (t < 640) {
        const int n = t % FH2, cc = t / FH2;   // 8 chunks of k=25
        float p = 0.0f;
        #pragma unroll 5
        for (int i = cc * 25; i < cc * 25 + 25; ++i) p += h1s[i] * fW2[i * FH2 + n];
        ph2[cc * FH2 + n] = p;
    }
    __syncthreads();
    if (t < FH2) {
        float a = fb2[t];
        #pragma unroll
        for (int cc = 0; cc < 8; ++cc) a += ph2[cc * FH2 + t];
        h2s[t] = fmaxf(a, 0.0f) + a2[t] * fminf(a, 0.0f);
    }
    __syncthreads();

    if (t < 128) {
        const int o = t >> 6;
        float p = h2s[lane] * fW3[lane * 2 + o];
        if (lane < 16) p += h2s[64 + lane] * fW3[(64 + lane) * 2 + o];
        #pragma unroll
        for (int off = 32; off > 0; off >>= 1) p += __shfl_down(p, off, 64);
        if (lane == 0) red2[o] = p + fb3[o];
    }
    __syncthreads();
    if (t == 0) {
        const float l0 = red2[0], l1 = red2[1];
        const float mx = fmaxf(l0, l1);
        const float e0 = __expf(l0 - mx), e1 = __expf(l1 - mx);
        const float invs = 1.0f / (e0 + e1);
        out[b * 2 + 0] = e0 * invs + 1e-8f;
        out[b * 2 + 1] = e1 * invs + 1e-8f;
    }
}

// ---------------------------------------------------------------------------
extern "C" void kernel_launch(void* const* d_in, const int* in_sizes, int n_in,
                              void* d_out, int out_size, void* d_ws, size_t ws_size,
                              hipStream_t stream) {
    const int*   mid          = (const int*)d_in[0];
    const int*   click_his    = (const int*)d_in[1];
    const int*   unclick_his  = (const int*)d_in[2];
    const float* click_mask   = (const float*)d_in[3];
    const float* unclick_mask = (const float*)d_in[4];
    const float* emb          = (const float*)d_in[5];
    const float* sW1 = (const float*)d_in[6];  const float* sb1 = (const float*)d_in[7];
    const float* sW2 = (const float*)d_in[8];  const float* sb2 = (const float*)d_in[9];
    const float* sW3 = (const float*)d_in[10]; const float* sb3 = (const float*)d_in[11];
    const float* cW1 = (const float*)d_in[12]; const float* cb1 = (const float*)d_in[13];
    const float* cW2 = (const float*)d_in[14]; const float* cb2 = (const float*)d_in[15];
    const float* cW3 = (const float*)d_in[16]; const float* cb3 = (const float*)d_in[17];
    const float* uW1 = (const float*)d_in[18]; const float* ub1 = (const float*)d_in[19];
    const float* uW2 = (const float*)d_in[20]; const float* ub2 = (const float*)d_in[21];
    const float* uW3 = (const float*)d_in[22]; const float* ub3 = (const float*)d_in[23];
    const float* bn_g = (const float*)d_in[24]; const float* bn_b = (const float*)d_in[25];
    const float* bn_m = (const float*)d_in[26]; const float* bn_v = (const float*)d_in[27];
    const float* fW1 = (const float*)d_in[28]; const float* fb1 = (const float*)d_in[29];
    const float* a1  = (const float*)d_in[30];
    const float* fW2 = (const float*)d_in[31]; const float* fb2 = (const float*)d_in[32];
    const float* a2  = (const float*)d_in[33];
    const float* fW3 = (const float*)d_in[34]; const float* fb3 = (const float*)d_in[35];

    float* out = (float*)d_out;

    // Workspace layout (bytes, 16B-aligned)
    char* w = (char*)d_ws;
    __bf16* Wt   = (__bf16*)(w + 0);       // 125952 B
    float* coef  = (float*)(w + 125952);   // 65536 B
    float* unatt = (float*)(w + 191488);   // 4194304 B

    hipLaunchKernelGGL(k_prep, dim3(3, 40), dim3(256), 0, stream,
        sW1, sW2, cW1, cW2, uW1, uW2, Wt);

    hipLaunchKernelGGL(k_din0, dim3(1024), dim3(640), 0, stream,
        click_his, unclick_his, click_mask, unclick_mask, emb, Wt,
        sb1, sb2, sW3, sb3, unatt, coef);

    hipLaunchKernelGGL(k_fused, dim3(BB), dim3(1024), 0, stream,
        mid, click_his, click_mask, emb, unatt, coef, Wt,
        cb1, cb2, cW3, cb3, ub1, ub2, uW3, ub3,
        bn_g, bn_b, bn_m, bn_v, fW1, fb1, a1, fW2, fb2, a2, fW3, fb3, out);
}